// Round 4
// baseline (512.319 us; speedup 1.0000x reference)
//
#include <hip/hip_runtime.h>

#define PI_F 3.14159265358979323846f

// out[b][p] = cos( (sum over 3 channels of 16 contiguous floats at
//                   in[b][c][p*16..p*16+16)) / 48 * pi/255 - pi/2 )
//
// Block = 256 threads handles 4 batch elements (48 KB). In float4 units a
// batch is 768 elements; positions tid, 256+tid, 512+tid are the SAME patch
// (p = tid>>2) in channels 0/1/2. Each thread: 4 batches x 3 = 12 independent
// float4 loads (each wave-instruction = contiguous 1 KB), summed per batch;
// two __shfl_xor across the aligned 4-lane group complete the 48-float patch
// sum; lane (tid&3)==0 applies cos and stores. No LDS, no barrier -> deep
// MLP (12 KB in flight per wave), low VGPR, 8 waves/SIMD.
__global__ __launch_bounds__(256) void qa_pool_cos_kernel(
    const float4* __restrict__ in4, float* __restrict__ out)
{
    int tid = threadIdx.x;                 // 0..255
    size_t b0   = (size_t)blockIdx.x * 4;  // first batch of this block
    size_t base = b0 * 768;                // float4 index of batch b0

    float s[4];
#pragma unroll
    for (int j = 0; j < 4; ++j) {
        size_t bb = base + (size_t)j * 768;
        float4 v0 = in4[bb + tid];         // channel 0, patch tid>>2
        float4 v1 = in4[bb + 256 + tid];   // channel 1, same patch
        float4 v2 = in4[bb + 512 + tid];   // channel 2, same patch
        s[j] = ((v0.x + v0.y) + (v0.z + v0.w))
             + ((v1.x + v1.y) + (v1.z + v1.w))
             + ((v2.x + v2.y) + (v2.z + v2.w));
    }

    // finish 48-float patch sums across the aligned 4-lane group
#pragma unroll
    for (int j = 0; j < 4; ++j) {
        s[j] += __shfl_xor(s[j], 1, 64);
        s[j] += __shfl_xor(s[j], 2, 64);
    }

    if ((tid & 3) == 0) {
        int p = tid >> 2;                  // 0..63
#pragma unroll
        for (int j = 0; j < 4; ++j) {
            float ang = s[j] * (1.0f / 48.0f) * (PI_F / 255.0f) - (PI_F * 0.5f);
            out[(b0 + j) * 64 + p] = __cosf(ang);
        }
    }
}

extern "C" void kernel_launch(void* const* d_in, const int* in_sizes, int n_in,
                              void* d_out, int out_size, void* d_ws, size_t ws_size,
                              hipStream_t stream) {
    const float4* in4 = (const float4*)d_in[0];
    float*        out = (float*)d_out;

    int B    = out_size / 64;              // 32768
    int grid = B / 4;                      // 4 batches per block
    qa_pool_cos_kernel<<<grid, 256, 0, stream>>>(in4, out);
}